// Round 1
// baseline (112.105 us; speedup 1.0000x reference)
//
#include <hip/hip_runtime.h>

#define NBOX 8192
#define TOP_K 50
#define IOU_THR 0.3f
#define VAR0 0.1f
#define VAR1 0.2f
#define NTHREADS 1024

__global__ __launch_bounds__(NTHREADS) void yunet_fused_kernel(
    const float* __restrict__ loc,    // [NBOX][14]
    const float* __restrict__ conf,   // [NBOX][2]
    const float* __restrict__ iou,    // [NBOX][1]
    const float* __restrict__ priors, // [NBOX][4]
    float* __restrict__ out)          // [TOP_K][15]
{
    // 64 KiB of LDS: sort keys; after NMS, first 50 ints are reused as keep_idx.
    __shared__ unsigned long long keys[NBOX];

    const int tid = threadIdx.x;

    // ---------------- Phase 1: build sort keys ----------------
    // score = sqrt(conf[:,1] * clip(iou, 0, 1)); key sorts by score DESC, idx ASC
    // (matches stable argsort(-scores)). score >= 0 so float bits are monotonic.
    for (int m = 0; m < NBOX / NTHREADS; ++m) {
        int i = tid + m * NTHREADS;
        float c = conf[i * 2 + 1];
        float u = iou[i];
        u = fminf(fmaxf(u, 0.0f), 1.0f);
        float s = sqrtf(c * u);
        unsigned sb = __float_as_uint(s);
        keys[i] = ((unsigned long long)(~sb) << 32) | (unsigned)i;
    }

    // ---------------- Phase 2: bitonic sort (ascending keys) ----------------
    for (unsigned k = 2; k <= NBOX; k <<= 1) {
        for (unsigned j = k >> 1; j > 0; j >>= 1) {
            __syncthreads();
            for (int m = 0; m < NBOX / NTHREADS; ++m) {
                unsigned i = (unsigned)tid + (unsigned)m * NTHREADS;
                unsigned l = i ^ j;
                if (l > i) {
                    unsigned long long a = keys[i];
                    unsigned long long b = keys[l];
                    bool asc = ((i & k) == 0);
                    if ((a > b) == asc) { keys[i] = b; keys[l] = a; }
                }
            }
        }
    }
    __syncthreads();

    // ---------------- Phase 3: greedy NMS (wave 0 only) ----------------
    if (tid < 64) {
        const int lane = tid;
        // this lane's kept box (lane k holds the k-th kept box)
        float kx1 = 0.f, ky1 = 0.f, kx2 = 0.f, ky2 = 0.f, karea = 0.f;
        int my_keep_idx = 0;   // original index this lane keeps (valid for lane < kept)
        int idx0 = 0;          // first kept original index (fill value)
        int kept = 0;
        bool done = false;

        for (int p = 0; p < NBOX && !done; p += 64) {
            // prefetch: each lane decodes candidate at sorted position p+lane
            int   cidx = 0;
            float x1 = 0.f, y1 = 0.f, x2 = 0.f, y2 = 0.f, area = 0.f;
            int pos = p + lane;
            if (pos < NBOX) {
                cidx = (int)(keys[pos] & 0xFFFFFFFFull);
                float pcx = priors[cidx * 4 + 0];
                float pcy = priors[cidx * 4 + 1];
                float pw  = priors[cidx * 4 + 2];
                float ph  = priors[cidx * 4 + 3];
                float l0 = loc[cidx * 14 + 0];
                float l1 = loc[cidx * 14 + 1];
                float l2 = loc[cidx * 14 + 2];
                float l3 = loc[cidx * 14 + 3];
                float cx = pcx + l0 * VAR0 * pw;
                float cy = pcy + l1 * VAR0 * ph;
                float hw = pw * expf(l2 * VAR0) * 0.5f;
                float hh = ph * expf(l3 * VAR1) * 0.5f;
                x1 = cx - hw; y1 = cy - hh; x2 = cx + hw; y2 = cy + hh;
                area = (x2 - x1) * (y2 - y1);
            }

            int nbatch = (NBOX - p) < 64 ? (NBOX - p) : 64;
            for (int c = 0; c < nbatch; ++c) {
                // broadcast candidate c to all lanes
                float bx1 = __shfl(x1, c);
                float by1 = __shfl(y1, c);
                float bx2 = __shfl(x2, c);
                float by2 = __shfl(y2, c);
                float barea = __shfl(area, c);
                int   bidx  = __shfl(cidx, c);

                // each lane < kept tests IoU of its kept box vs candidate
                float iw = fminf(kx2, bx2) - fmaxf(kx1, bx1);
                float ih = fminf(ky2, by2) - fmaxf(ky1, by1);
                iw = fmaxf(iw, 0.0f);
                ih = fmaxf(ih, 0.0f);
                float inter = iw * ih;
                float v = inter / (karea + barea - inter);
                bool sup = (lane < kept) && (v > IOU_THR);
                unsigned long long mask = __ballot(sup);
                if (mask == 0ull) {
                    if (kept == 0) idx0 = bidx;
                    if (lane == kept) {
                        kx1 = bx1; ky1 = by1; kx2 = bx2; ky2 = by2; karea = barea;
                        my_keep_idx = bidx;
                    }
                    ++kept;
                    if (kept == TOP_K) { done = true; break; }
                }
            }
        }

        // write keep indices into LDS (reuse keys storage); fill w/ first kept
        int* kout = (int*)keys;
        if (lane < TOP_K) {
            kout[lane] = (lane < kept) ? my_keep_idx : idx0;
        }
    }
    __syncthreads();

    // ---------------- Phase 4: gather + decode output rows ----------------
    if (tid < TOP_K) {
        const int* kidx = (const int*)keys;
        int i = kidx[tid];
        float pcx = priors[i * 4 + 0];
        float pcy = priors[i * 4 + 1];
        float pw  = priors[i * 4 + 2];
        float ph  = priors[i * 4 + 3];
        float l0 = loc[i * 14 + 0];
        float l1 = loc[i * 14 + 1];
        float l2 = loc[i * 14 + 2];
        float l3 = loc[i * 14 + 3];
        float cx = pcx + l0 * VAR0 * pw;
        float cy = pcy + l1 * VAR0 * ph;
        float hw = pw * expf(l2 * VAR0) * 0.5f;
        float hh = ph * expf(l3 * VAR1) * 0.5f;
        float* o = out + tid * 15;
        o[0] = cx - hw;
        o[1] = cy - hh;
        o[2] = cx + hw;
        o[3] = cy + hh;
        #pragma unroll
        for (int q = 0; q < 5; ++q) {
            o[4 + 2 * q] = pcx + loc[i * 14 + 4 + 2 * q] * VAR0 * pw;
            o[5 + 2 * q] = pcy + loc[i * 14 + 5 + 2 * q] * VAR0 * ph;
        }
        float cc = conf[i * 2 + 1];
        float u  = fminf(fmaxf(iou[i], 0.0f), 1.0f);
        o[14] = sqrtf(cc * u);
    }
}

extern "C" void kernel_launch(void* const* d_in, const int* in_sizes, int n_in,
                              void* d_out, int out_size, void* d_ws, size_t ws_size,
                              hipStream_t stream) {
    const float* loc    = (const float*)d_in[0];
    const float* conf   = (const float*)d_in[1];
    const float* iou    = (const float*)d_in[2];
    const float* priors = (const float*)d_in[3];
    float* out = (float*)d_out;

    yunet_fused_kernel<<<1, NTHREADS, 0, stream>>>(loc, conf, iou, priors, out);
}

// Round 2
// 58.478 us; speedup vs baseline: 1.9170x; 1.9170x over previous
//
#include <hip/hip_runtime.h>

#define NBOX 8192
#define TOP_K 50
#define IOU_THR 0.3f
#define VAR0 0.1f
#define VAR1 0.2f
#define NT 256
#define MSEL 256          // select at least this many top candidates
#define CAND_MAX 1024

__device__ __forceinline__ void decode_box(int cidx, const float* __restrict__ loc,
                                           const float* __restrict__ priors,
                                           float& x1, float& y1, float& x2, float& y2,
                                           float& area)
{
    float pcx = priors[cidx * 4 + 0];
    float pcy = priors[cidx * 4 + 1];
    float pw  = priors[cidx * 4 + 2];
    float ph  = priors[cidx * 4 + 3];
    float cx = pcx + loc[cidx * 14 + 0] * VAR0 * pw;
    float cy = pcy + loc[cidx * 14 + 1] * VAR0 * ph;
    float hw = pw * expf(loc[cidx * 14 + 2] * VAR0) * 0.5f;
    float hh = ph * expf(loc[cidx * 14 + 3] * VAR1) * 0.5f;
    x1 = cx - hw; y1 = cy - hh; x2 = cx + hw; y2 = cy + hh;
    area = (x2 - x1) * (y2 - y1);
}

// Greedy NMS over sorted keys arr[0..n). Wave 0 only (lane = tid 0..63).
// Fills keep_out[0..TOP_K) (fill value = first box in sorted order).
// Returns kept count (capped at TOP_K).
__device__ int greedy_nms(const unsigned long long* __restrict__ arr, int n, int lane,
                          const float* __restrict__ loc, const float* __restrict__ priors,
                          int* keep_out)
{
    float kx1 = 0.f, ky1 = 0.f, kx2 = 0.f, ky2 = 0.f, karea = 0.f;
    int my_keep = 0, idx0 = 0, kept = 0;
    bool done = false;

    for (int p = 0; p < n && !done; p += 64) {
        int cidx = 0;
        float x1 = 0.f, y1 = 0.f, x2 = 0.f, y2 = 0.f, area = 0.f;
        int pos = p + lane;
        if (pos < n) {
            cidx = (int)(arr[pos] & 0xFFFFFFFFull);
            decode_box(cidx, loc, priors, x1, y1, x2, y2, area);
        }
        int nb = (n - p) < 64 ? (n - p) : 64;
        for (int c = 0; c < nb; ++c) {
            float bx1 = __shfl(x1, c);
            float by1 = __shfl(y1, c);
            float bx2 = __shfl(x2, c);
            float by2 = __shfl(y2, c);
            float barea = __shfl(area, c);
            int   bidx  = __shfl(cidx, c);

            float iw = fmaxf(fminf(kx2, bx2) - fmaxf(kx1, bx1), 0.0f);
            float ih = fmaxf(fminf(ky2, by2) - fmaxf(ky1, by1), 0.0f);
            float inter = iw * ih;
            float v = inter / (karea + barea - inter);
            bool sup = (lane < kept) && (v > IOU_THR);
            unsigned long long mask = __ballot(sup);
            if (mask == 0ull) {
                if (kept == 0) idx0 = bidx;
                if (lane == kept) {
                    kx1 = bx1; ky1 = by1; kx2 = bx2; ky2 = by2; karea = barea;
                    my_keep = bidx;
                }
                ++kept;
                if (kept == TOP_K) { done = true; break; }
            }
        }
    }
    if (lane < TOP_K) keep_out[lane] = (lane < kept) ? my_keep : idx0;
    return kept;
}

// Block-uniform bitonic sort (ascending) of a[0..S). S = power of two.
__device__ void bitonic_sort(unsigned long long* a, int S, int tid)
{
    for (int k = 2; k <= S; k <<= 1) {
        for (int j = k >> 1; j > 0; j >>= 1) {
            __syncthreads();
            for (int i = tid; i < S; i += NT) {
                int l = i ^ j;
                if (l > i) {
                    unsigned long long A = a[i];
                    unsigned long long B = a[l];
                    bool asc = ((i & k) == 0);
                    if ((A > B) == asc) { a[i] = B; a[l] = A; }
                }
            }
        }
    }
    __syncthreads();
}

__global__ __launch_bounds__(NT) void yunet_fused_kernel(
    const float* __restrict__ loc,    // [NBOX][14]
    const float* __restrict__ conf,   // [NBOX][2]
    const float* __restrict__ iou,    // [NBOX][1]
    const float* __restrict__ priors, // [NBOX][4]
    float* __restrict__ out)          // [TOP_K][15]
{
    __shared__ unsigned long long keys[NBOX];     // 64 KiB: all keys (fallback path)
    __shared__ unsigned long long cand[CAND_MAX]; // 8 KiB: selected top candidates
    __shared__ unsigned int hist[256];
    __shared__ unsigned int sh_cnt, sh_above, sh_T;
    __shared__ int sh_B, sh_flag;
    __shared__ int keep_sh[TOP_K];

    const int tid = threadIdx.x;

    hist[tid] = 0;
    if (tid == 0) { sh_cnt = 0; sh_flag = 0; }
    __syncthreads();

    // ---- Phase 1: scores -> 64-bit sort keys + coarse histogram (top 8 bits) ----
    // key = (~score_bits)<<32 | idx  => ascending sort == score desc, idx asc (stable)
    for (int m = 0; m < NBOX / (NT * 4); ++m) {
        int i = m * NT * 4 + tid * 4;
        float4 cf0 = *reinterpret_cast<const float4*>(conf + 2 * i);
        float4 cf1 = *reinterpret_cast<const float4*>(conf + 2 * i + 4);
        float4 io  = *reinterpret_cast<const float4*>(iou + i);
        float cs[4] = {cf0.y, cf0.w, cf1.y, cf1.w};
        float us[4] = {io.x, io.y, io.z, io.w};
        #pragma unroll
        for (int q = 0; q < 4; ++q) {
            float u = fminf(fmaxf(us[q], 0.0f), 1.0f);
            float s = sqrtf(cs[q] * u);
            unsigned sb = __float_as_uint(s);   // s >= 0 -> bits monotonic in s
            keys[i + q] = ((unsigned long long)(~sb) << 32) | (unsigned)(i + q);
            atomicAdd(&hist[sb >> 24], 1u);
        }
    }
    __syncthreads();

    // ---- Phase 2a: coarse threshold bin B (from the top) ----
    if (tid == 0) {
        unsigned acc = 0; int B = 0; unsigned above = 0;
        for (int b = 255; b >= 0; --b) {
            unsigned nb = acc + hist[b];
            if (nb >= MSEL) { B = b; above = acc; break; }
            acc = nb;
            if (b == 0) { B = 0; above = acc; }
        }
        sh_B = B; sh_above = above;
    }
    __syncthreads();
    const int B = sh_B;

    hist[tid] = 0;           // reuse for fine histogram
    __syncthreads();

    // ---- Phase 2b: fine histogram (next 8 bits) within bin B ----
    for (int i = tid; i < NBOX; i += NT) {
        unsigned sb = ~(unsigned)(keys[i] >> 32);
        if ((int)(sb >> 24) == B) atomicAdd(&hist[(sb >> 16) & 255u], 1u);
    }
    __syncthreads();

    if (tid == 0) {
        unsigned acc = sh_above;
        unsigned T = ((unsigned)B << 24);
        for (int f = 255; f >= 0; --f) {
            acc += hist[f];
            if (acc >= MSEL) { T = ((unsigned)B << 24) | ((unsigned)f << 16); break; }
            if (f == 0)      { T = ((unsigned)B << 24); }
        }
        sh_T = T;
    }
    __syncthreads();
    const unsigned T = sh_T;

    // ---- Phase 3: compact candidates with sb >= T (order irrelevant; sorted next) ----
    for (int i = tid; i < NBOX; i += NT) {
        unsigned sb = ~(unsigned)(keys[i] >> 32);
        if (sb >= T) {
            unsigned pos = atomicAdd(&sh_cnt, 1u);
            if (pos < CAND_MAX) cand[pos] = keys[i];
        }
    }
    __syncthreads();
    const int C = (int)sh_cnt;

    if (C <= CAND_MAX) {
        // ---- Phase 4: pad to pow2, sort the small candidate list ----
        int P = MSEL;
        while (P < C) P <<= 1;
        for (int i = tid; i < P; i += NT)
            if (i >= C) cand[i] = ~0ull;
        bitonic_sort(cand, P, tid);   // starts with __syncthreads()

        // ---- Phase 5: greedy NMS with early exit at TOP_K kept ----
        if (tid < 64) {
            int kept = greedy_nms(cand, C, tid, loc, priors, keep_sh);
            if (tid == 0) sh_flag = (kept == TOP_K) ? 0 : 1;
        }
    } else {
        if (tid == 0) sh_flag = 1;   // selection overflow -> full path
    }
    __syncthreads();

    // ---- Fallback (deterministic, exact; never triggers unless candidates ran out) ----
    if (sh_flag) {
        bitonic_sort(keys, NBOX, tid);
        if (tid < 64) greedy_nms(keys, NBOX, tid, loc, priors, keep_sh);
        __syncthreads();
    }

    // ---- Phase 6: gather + decode output rows ----
    if (tid < TOP_K) {
        int i = keep_sh[tid];
        float pcx = priors[i * 4 + 0];
        float pcy = priors[i * 4 + 1];
        float pw  = priors[i * 4 + 2];
        float ph  = priors[i * 4 + 3];
        float cx = pcx + loc[i * 14 + 0] * VAR0 * pw;
        float cy = pcy + loc[i * 14 + 1] * VAR0 * ph;
        float hw = pw * expf(loc[i * 14 + 2] * VAR0) * 0.5f;
        float hh = ph * expf(loc[i * 14 + 3] * VAR1) * 0.5f;
        float* o = out + tid * 15;
        o[0] = cx - hw;
        o[1] = cy - hh;
        o[2] = cx + hw;
        o[3] = cy + hh;
        #pragma unroll
        for (int q = 0; q < 5; ++q) {
            o[4 + 2 * q] = pcx + loc[i * 14 + 4 + 2 * q] * VAR0 * pw;
            o[5 + 2 * q] = pcy + loc[i * 14 + 5 + 2 * q] * VAR0 * ph;
        }
        float cc = conf[i * 2 + 1];
        float u  = fminf(fmaxf(iou[i], 0.0f), 1.0f);
        o[14] = sqrtf(cc * u);
    }
}

extern "C" void kernel_launch(void* const* d_in, const int* in_sizes, int n_in,
                              void* d_out, int out_size, void* d_ws, size_t ws_size,
                              hipStream_t stream) {
    const float* loc    = (const float*)d_in[0];
    const float* conf   = (const float*)d_in[1];
    const float* iou    = (const float*)d_in[2];
    const float* priors = (const float*)d_in[3];
    float* out = (float*)d_out;

    yunet_fused_kernel<<<1, NT, 0, stream>>>(loc, conf, iou, priors, out);
}

// Round 3
// 28.736 us; speedup vs baseline: 3.9012x; 2.0350x over previous
//
#include <hip/hip_runtime.h>

#define NBOX 8192
#define TOP_K 50
#define IOU_THR 0.3f
#define VAR0 0.1f
#define VAR1 0.2f
#define NT 512
#define NWAVE (NT / 64)
#define MSEL 256
#define CAND_MAX 1024
#define BPT 16          // boxes per thread

__device__ __forceinline__ void decode_box(int cidx, const float* __restrict__ loc,
                                           const float* __restrict__ priors,
                                           float& x1, float& y1, float& x2, float& y2,
                                           float& area)
{
    float4 pr = *reinterpret_cast<const float4*>(priors + 4 * cidx);  // 16B aligned
    float l0 = loc[cidx * 14 + 0];
    float l1 = loc[cidx * 14 + 1];
    float l2 = loc[cidx * 14 + 2];
    float l3 = loc[cidx * 14 + 3];
    float cx = pr.x + l0 * VAR0 * pr.z;
    float cy = pr.y + l1 * VAR0 * pr.w;
    float hw = pr.z * expf(l2 * VAR0) * 0.5f;
    float hh = pr.w * expf(l3 * VAR1) * 0.5f;
    x1 = cx - hw; y1 = cy - hh; x2 = cx + hw; y2 = cy + hh;
    area = (x2 - x1) * (y2 - y1);
}

// Wave-0 helper: bins[4*lane .. 4*lane+3] (c0..c3), higher bin = higher score.
// Finds bin B (and count strictly above it) s.t. cumulative-from-top first reaches MSEL.
__device__ __forceinline__ void find_thresh(unsigned c0, unsigned c1, unsigned c2, unsigned c3,
                                            unsigned base_above, int lane,
                                            int& bin_sel, unsigned& above_sel)
{
    unsigned cnt = c0 + c1 + c2 + c3;
    unsigned S = cnt;                       // suffix sum over lanes >= lane
    #pragma unroll
    for (int d = 1; d < 64; d <<= 1) {
        unsigned t = __shfl_down(S, d);
        if (lane + d < 64) S += t;
    }
    unsigned long long bal = __ballot(base_above + S >= MSEL);
    int lstar = 63 - __clzll(bal);          // bal != 0 guaranteed by construction
    int src = (lstar < 63) ? (lstar + 1) : lstar;
    unsigned Snext = __shfl(S, src);
    unsigned above = base_above + ((lstar < 63) ? Snext : 0u);
    unsigned bl[4] = {c0, c1, c2, c3};
    int bsel = -1; unsigned abv = above; unsigned acc = above;
    #pragma unroll
    for (int k = 3; k >= 0; --k) {
        if (bsel < 0) {
            if (acc + bl[k] >= MSEL) { bsel = k; abv = acc; }
            else acc += bl[k];
        }
    }
    bin_sel  = 4 * lstar + __shfl(bsel, lstar);
    above_sel = __shfl(abv, lstar);
}

// ---- fallback machinery (exact, rarely/never taken on this data) ----
__device__ void bitonic_sort(unsigned long long* a, int S, int tid)
{
    for (int k = 2; k <= S; k <<= 1) {
        for (int j = k >> 1; j > 0; j >>= 1) {
            __syncthreads();
            for (int i = tid; i < S; i += NT) {
                int l = i ^ j;
                if (l > i) {
                    unsigned long long A = a[i];
                    unsigned long long B = a[l];
                    bool asc = ((i & k) == 0);
                    if ((A > B) == asc) { a[i] = B; a[l] = A; }
                }
            }
        }
    }
    __syncthreads();
}

__device__ int greedy_nms_serial(const unsigned long long* __restrict__ arr, int n, int lane,
                                 const float* __restrict__ loc, const float* __restrict__ priors,
                                 int* keep_out)
{
    float kx1 = 0.f, ky1 = 0.f, kx2 = 0.f, ky2 = 0.f, karea = 0.f;
    int my_keep = 0, idx0 = 0, kept = 0;
    bool done = false;
    for (int p = 0; p < n && !done; p += 64) {
        int cidx = 0;
        float x1 = 0.f, y1 = 0.f, x2 = 0.f, y2 = 0.f, area = 0.f;
        int pos = p + lane;
        if (pos < n) {
            cidx = (int)(arr[pos] & 0xFFFFFFFFull);
            decode_box(cidx, loc, priors, x1, y1, x2, y2, area);
        }
        int nb = (n - p) < 64 ? (n - p) : 64;
        for (int c = 0; c < nb; ++c) {
            float bx1 = __shfl(x1, c);
            float by1 = __shfl(y1, c);
            float bx2 = __shfl(x2, c);
            float by2 = __shfl(y2, c);
            float barea = __shfl(area, c);
            int   bidx  = __shfl(cidx, c);
            float iw = fmaxf(fminf(kx2, bx2) - fmaxf(kx1, bx1), 0.0f);
            float ih = fmaxf(fminf(ky2, by2) - fmaxf(ky1, by1), 0.0f);
            float inter = iw * ih;
            float v = inter / (karea + barea - inter);
            bool sup = (lane < kept) && (v > IOU_THR);
            if (__ballot(sup) == 0ull) {
                if (kept == 0) idx0 = bidx;
                if (lane == kept) {
                    kx1 = bx1; ky1 = by1; kx2 = bx2; ky2 = by2; karea = barea;
                    my_keep = bidx;
                }
                ++kept;
                if (kept == TOP_K) { done = true; break; }
            }
        }
    }
    if (lane < TOP_K) keep_out[lane] = (lane < kept) ? my_keep : idx0;
    return kept;
}

__global__ __launch_bounds__(NT) void yunet_fused_kernel(
    const float* __restrict__ loc,    // [NBOX][14]
    const float* __restrict__ conf,   // [NBOX][2]
    const float* __restrict__ iou,    // [NBOX][1]
    const float* __restrict__ priors, // [NBOX][4]
    float* __restrict__ out)          // [TOP_K][15]
{
    __shared__ unsigned long long keys[NBOX];      // fallback space; main path: rank-sorted cands
    __shared__ unsigned long long cand[CAND_MAX];
    __shared__ unsigned int hist[NWAVE][256];
    __shared__ unsigned int fhist[256];
    __shared__ unsigned long long maskbuf[64];
    __shared__ float4 boxb4[64];
    __shared__ float  boxa[64];
    __shared__ float4 keptb4[TOP_K];
    __shared__ float  kepta[TOP_K];
    __shared__ int keep_sh[TOP_K];
    __shared__ unsigned sh_cnt, sh_above, sh_T;
    __shared__ int sh_B, sh_flag;

    const int tid = threadIdx.x;

    // ---- Phase 0: zero histograms/control ----
    {
        unsigned* hz = &hist[0][0];
        for (int i = tid; i < NWAVE * 256; i += NT) hz[i] = 0;
        for (int i = tid; i < 256; i += NT) fhist[i] = 0;
        if (tid == 0) { sh_cnt = 0; sh_flag = 0; }
    }
    __syncthreads();

    // ---- Phase 1: compute score bits (registers) + per-wave coarse histogram ----
    unsigned sbv[BPT];
    const float4* conf4 = reinterpret_cast<const float4*>(conf);
    const float4* iou4  = reinterpret_cast<const float4*>(iou);
    #pragma unroll
    for (int m = 0; m < 2; ++m) {
        int base = (m * NT + tid) * 8;
        float sc[8], uu[8];
        #pragma unroll
        for (int q = 0; q < 4; ++q) {
            float4 cf = conf4[base / 2 + q];
            sc[2 * q] = cf.y; sc[2 * q + 1] = cf.w;
        }
        #pragma unroll
        for (int r = 0; r < 2; ++r) {
            float4 io = iou4[base / 4 + r];
            uu[4 * r + 0] = io.x; uu[4 * r + 1] = io.y;
            uu[4 * r + 2] = io.z; uu[4 * r + 3] = io.w;
        }
        #pragma unroll
        for (int q = 0; q < 8; ++q) {
            float u = fminf(fmaxf(uu[q], 0.0f), 1.0f);
            float s = sqrtf(sc[q] * u);
            unsigned sb = __float_as_uint(s);   // s >= 0 -> monotonic bits
            sbv[m * 8 + q] = sb;
            atomicAdd(&hist[tid >> 6][sb >> 24], 1u);
        }
    }
    __syncthreads();

    // ---- Phase 2a: coarse threshold (wave-parallel suffix scan) ----
    if (tid < 64) {
        const int lane = tid;
        unsigned c0 = 0, c1 = 0, c2 = 0, c3 = 0;
        #pragma unroll
        for (int w = 0; w < NWAVE; ++w) {
            c0 += hist[w][4 * lane + 0];
            c1 += hist[w][4 * lane + 1];
            c2 += hist[w][4 * lane + 2];
            c3 += hist[w][4 * lane + 3];
        }
        int bs; unsigned ab;
        find_thresh(c0, c1, c2, c3, 0u, lane, bs, ab);
        if (lane == 0) { sh_B = bs; sh_above = ab; }
    }
    __syncthreads();
    const int B = sh_B;
    const unsigned above = sh_above;

    // ---- Phase 2b: fine histogram (register scan, no LDS key re-read) ----
    #pragma unroll
    for (int k = 0; k < BPT; ++k) {
        unsigned sb = sbv[k];
        if ((int)(sb >> 24) == B) atomicAdd(&fhist[(sb >> 16) & 255u], 1u);
    }
    __syncthreads();

    if (tid < 64) {
        const int lane = tid;
        unsigned c0 = fhist[4 * lane + 0];
        unsigned c1 = fhist[4 * lane + 1];
        unsigned c2 = fhist[4 * lane + 2];
        unsigned c3 = fhist[4 * lane + 3];
        int fs; unsigned ab2;
        find_thresh(c0, c1, c2, c3, above, lane, fs, ab2);
        if (lane == 0) sh_T = ((unsigned)B << 24) | ((unsigned)fs << 16);
    }
    __syncthreads();
    const unsigned T = sh_T;

    // ---- Phase 3: compact candidates (register scan) ----
    #pragma unroll
    for (int m = 0; m < 2; ++m) {
        #pragma unroll
        for (int q = 0; q < 8; ++q) {
            unsigned sb = sbv[m * 8 + q];
            if (sb >= T) {
                unsigned pos = atomicAdd(&sh_cnt, 1u);
                if (pos < CAND_MAX)
                    cand[pos] = ((unsigned long long)(~sb) << 32)
                              | (unsigned)((m * NT + tid) * 8 + q);
            }
        }
    }
    __syncthreads();
    const int C = (int)sh_cnt;

    if (C <= CAND_MAX) {
        // ---- Phase 4: exact rank sort (keys unique; broadcast LDS reads) ----
        for (int i = tid; i < C; i += NT) {
            unsigned long long k = cand[i];
            int r = 0;
            for (int j = 0; j < C; ++j) r += (cand[j] < k) ? 1 : 0;
            keys[r] = k;    // keys[] doubles as sorted candidate list
        }
        __syncthreads();

        // ---- Phase 5: batch-mask greedy NMS (wave 0) ----
        if (tid < 64) {
            const int lane = tid;
            int kept = 0;
            for (int p = 0; p < C && kept < TOP_K; p += 64) {
                int pos = p + lane;
                bool valid = pos < C;
                int cidx = valid ? (int)(keys[pos] & 0xFFFFFFFFull) : 0;
                float x1, y1, x2, y2, area;
                decode_box(cidx, loc, priors, x1, y1, x2, y2, area);
                boxb4[lane] = make_float4(x1, y1, x2, y2);
                boxa[lane] = area;
                __asm__ volatile("s_waitcnt lgkmcnt(0)" ::: "memory");

                // suppression by previously-kept boxes
                bool supP = !valid;
                for (int j = 0; j < kept; ++j) {
                    float4 kb = keptb4[j]; float ka = kepta[j];
                    float iw = fmaxf(fminf(x2, kb.z) - fmaxf(x1, kb.x), 0.f);
                    float ih = fmaxf(fminf(y2, kb.w) - fmaxf(y1, kb.y), 0.f);
                    float inter = iw * ih;
                    supP = supP || (inter / (area + ka - inter) > IOU_THR);
                }
                unsigned long long sup_prev = __ballot(supP);

                // 64x64 IoU bit-matrix vs current batch (parallel)
                unsigned long long mask = 0ull;
                for (int j = 0; j < 64; ++j) {
                    float4 kb = boxb4[j]; float ka = boxa[j];
                    float iw = fmaxf(fminf(x2, kb.z) - fmaxf(x1, kb.x), 0.f);
                    float ih = fmaxf(fminf(y2, kb.w) - fmaxf(y1, kb.y), 0.f);
                    float inter = iw * ih;
                    mask |= ((unsigned long long)((inter / (area + ka - inter)) > IOU_THR)) << j;
                }
                maskbuf[lane] = mask;
                __asm__ volatile("s_waitcnt lgkmcnt(0)" ::: "memory");

                // exact greedy recurrence on bitmasks (uniform across lanes)
                unsigned long long keepcur = 0ull;
                for (int i2 = 0; i2 < 64; ++i2) {
                    if (!((sup_prev >> i2) & 1ull)) {
                        unsigned long long mi = maskbuf[i2];
                        unsigned long long lower = (i2 == 0) ? 0ull : (~0ull >> (64 - i2));
                        if ((mi & keepcur & lower) == 0ull) keepcur |= (1ull << i2);
                    }
                }

                unsigned long long lowm = (lane == 0) ? 0ull : (~0ull >> (64 - lane));
                int rank = kept + __popcll(keepcur & lowm);
                if (((keepcur >> lane) & 1ull) && rank < TOP_K) {
                    keep_sh[rank] = cidx;
                    keptb4[rank] = make_float4(x1, y1, x2, y2);
                    kepta[rank] = area;
                }
                kept += __popcll(keepcur);
                __asm__ volatile("s_waitcnt lgkmcnt(0)" ::: "memory");
            }
            if (lane == 0) sh_flag = (kept >= TOP_K) ? 0 : 1;
        }
    } else {
        if (tid == 0) sh_flag = 1;
    }
    __syncthreads();

    // ---- Fallback: exact full path (sort all + serial NMS w/ fill) ----
    if (sh_flag) {
        #pragma unroll
        for (int m = 0; m < 2; ++m) {
            #pragma unroll
            for (int q = 0; q < 8; ++q) {
                int i = (m * NT + tid) * 8 + q;
                keys[i] = ((unsigned long long)(~sbv[m * 8 + q]) << 32) | (unsigned)i;
            }
        }
        __syncthreads();
        bitonic_sort(keys, NBOX, tid);
        if (tid < 64) greedy_nms_serial(keys, NBOX, tid, loc, priors, keep_sh);
        __syncthreads();
    }

    // ---- Phase 6: gather + decode output rows ----
    if (tid < TOP_K) {
        int i = keep_sh[tid];
        float4 pr = *reinterpret_cast<const float4*>(priors + 4 * i);
        float cx = pr.x + loc[i * 14 + 0] * VAR0 * pr.z;
        float cy = pr.y + loc[i * 14 + 1] * VAR0 * pr.w;
        float hw = pr.z * expf(loc[i * 14 + 2] * VAR0) * 0.5f;
        float hh = pr.w * expf(loc[i * 14 + 3] * VAR1) * 0.5f;
        float* o = out + tid * 15;
        o[0] = cx - hw;
        o[1] = cy - hh;
        o[2] = cx + hw;
        o[3] = cy + hh;
        #pragma unroll
        for (int q = 0; q < 5; ++q) {
            o[4 + 2 * q] = pr.x + loc[i * 14 + 4 + 2 * q] * VAR0 * pr.z;
            o[5 + 2 * q] = pr.y + loc[i * 14 + 5 + 2 * q] * VAR0 * pr.w;
        }
        float cc = conf[i * 2 + 1];
        float u  = fminf(fmaxf(iou[i], 0.0f), 1.0f);
        o[14] = sqrtf(cc * u);
    }
}

extern "C" void kernel_launch(void* const* d_in, const int* in_sizes, int n_in,
                              void* d_out, int out_size, void* d_ws, size_t ws_size,
                              hipStream_t stream) {
    const float* loc    = (const float*)d_in[0];
    const float* conf   = (const float*)d_in[1];
    const float* iou    = (const float*)d_in[2];
    const float* priors = (const float*)d_in[3];
    float* out = (float*)d_out;

    yunet_fused_kernel<<<1, NT, 0, stream>>>(loc, conf, iou, priors, out);
}

// Round 4
// 23.272 us; speedup vs baseline: 4.8172x; 1.2348x over previous
//
#include <hip/hip_runtime.h>

#define NBOX 8192
#define TOP_K 50
#define IOU_THR 0.3f
#define VAR0 0.1f
#define VAR1 0.2f
#define NT 512
#define NWAVE (NT / 64)
#define MSEL 128
#define CAND_MAX 1024
#define BPT 16          // boxes per thread

__device__ __forceinline__ void decode_box(int cidx, const float* __restrict__ loc,
                                           const float* __restrict__ priors,
                                           float& x1, float& y1, float& x2, float& y2,
                                           float& area)
{
    float4 pr = *reinterpret_cast<const float4*>(priors + 4 * cidx);
    float l0 = loc[cidx * 14 + 0];
    float l1 = loc[cidx * 14 + 1];
    float l2 = loc[cidx * 14 + 2];
    float l3 = loc[cidx * 14 + 3];
    float cx = pr.x + l0 * VAR0 * pr.z;
    float cy = pr.y + l1 * VAR0 * pr.w;
    float hw = pr.z * expf(l2 * VAR0) * 0.5f;
    float hh = pr.w * expf(l3 * VAR1) * 0.5f;
    x1 = cx - hw; y1 = cy - hh; x2 = cx + hw; y2 = cy + hh;
    area = (x2 - x1) * (y2 - y1);
}

// Wave-0 helper: bins[4*lane .. 4*lane+3] (c0..c3), higher bin = higher score.
__device__ __forceinline__ void find_thresh(unsigned c0, unsigned c1, unsigned c2, unsigned c3,
                                            unsigned base_above, int lane,
                                            int& bin_sel, unsigned& above_sel)
{
    unsigned cnt = c0 + c1 + c2 + c3;
    unsigned S = cnt;                       // suffix sum over lanes >= lane
    #pragma unroll
    for (int d = 1; d < 64; d <<= 1) {
        unsigned t = __shfl_down(S, d);
        if (lane + d < 64) S += t;
    }
    unsigned long long bal = __ballot(base_above + S >= MSEL);
    int lstar = 63 - __clzll(bal);
    int src = (lstar < 63) ? (lstar + 1) : lstar;
    unsigned Snext = __shfl(S, src);
    unsigned above = base_above + ((lstar < 63) ? Snext : 0u);
    unsigned bl[4] = {c0, c1, c2, c3};
    int bsel = -1; unsigned abv = above; unsigned acc = above;
    #pragma unroll
    for (int k = 3; k >= 0; --k) {
        if (bsel < 0) {
            if (acc + bl[k] >= MSEL) { bsel = k; abv = acc; }
            else acc += bl[k];
        }
    }
    bin_sel  = 4 * lstar + __shfl(bsel, lstar);
    above_sel = __shfl(abv, lstar);
}

// ---- fallback machinery (exact; never taken on this data) ----
__device__ void bitonic_sort(unsigned long long* a, int S, int tid)
{
    for (int k = 2; k <= S; k <<= 1) {
        for (int j = k >> 1; j > 0; j >>= 1) {
            __syncthreads();
            for (int i = tid; i < S; i += NT) {
                int l = i ^ j;
                if (l > i) {
                    unsigned long long A = a[i];
                    unsigned long long B = a[l];
                    bool asc = ((i & k) == 0);
                    if ((A > B) == asc) { a[i] = B; a[l] = A; }
                }
            }
        }
    }
    __syncthreads();
}

__device__ int greedy_nms_serial(const unsigned long long* __restrict__ arr, int n, int lane,
                                 const float* __restrict__ loc, const float* __restrict__ priors,
                                 int* keep_out)
{
    float kx1 = 0.f, ky1 = 0.f, kx2 = 0.f, ky2 = 0.f, karea = 0.f;
    int my_keep = 0, idx0 = 0, kept = 0;
    bool done = false;
    for (int p = 0; p < n && !done; p += 64) {
        int cidx = 0;
        float x1 = 0.f, y1 = 0.f, x2 = 0.f, y2 = 0.f, area = 0.f;
        int pos = p + lane;
        if (pos < n) {
            cidx = (int)(arr[pos] & 0xFFFFFFFFull);
            decode_box(cidx, loc, priors, x1, y1, x2, y2, area);
        }
        int nb = (n - p) < 64 ? (n - p) : 64;
        for (int c = 0; c < nb; ++c) {
            float bx1 = __shfl(x1, c);
            float by1 = __shfl(y1, c);
            float bx2 = __shfl(x2, c);
            float by2 = __shfl(y2, c);
            float barea = __shfl(area, c);
            int   bidx  = __shfl(cidx, c);
            float iw = fmaxf(fminf(kx2, bx2) - fmaxf(kx1, bx1), 0.0f);
            float ih = fmaxf(fminf(ky2, by2) - fmaxf(ky1, by1), 0.0f);
            float inter = iw * ih;
            float v = inter / (karea + barea - inter);
            bool sup = (lane < kept) && (v > IOU_THR);
            if (__ballot(sup) == 0ull) {
                if (kept == 0) idx0 = bidx;
                if (lane == kept) {
                    kx1 = bx1; ky1 = by1; kx2 = bx2; ky2 = by2; karea = barea;
                    my_keep = bidx;
                }
                ++kept;
                if (kept == TOP_K) { done = true; break; }
            }
        }
    }
    if (lane < TOP_K) keep_out[lane] = (lane < kept) ? my_keep : idx0;
    return kept;
}

__global__ __launch_bounds__(NT) void yunet_fused_kernel(
    const float* __restrict__ loc,    // [NBOX][14]
    const float* __restrict__ conf,   // [NBOX][2]
    const float* __restrict__ iou,    // [NBOX][1]
    const float* __restrict__ priors, // [NBOX][4]
    float* __restrict__ out)          // [TOP_K][15]
{
    __shared__ unsigned long long keys[NBOX];      // fallback space; main path: rank-sorted cands
    __shared__ unsigned long long cand[CAND_MAX];
    __shared__ unsigned int hist[NWAVE][256];
    __shared__ unsigned int fhist[256];
    __shared__ unsigned long long maskbuf[64];
    __shared__ unsigned long long sh_supprev;
    __shared__ float4 boxb4[64];
    __shared__ float  boxa[64];
    __shared__ float4 keptb4[TOP_K];
    __shared__ float  kepta[TOP_K];
    __shared__ int keep_sh[TOP_K];
    __shared__ unsigned sh_cnt, sh_above, sh_T;
    __shared__ int sh_B, sh_flag, sh_kept;

    const int tid = threadIdx.x;

    // ---- Phase 0: zero histograms/control ----
    {
        unsigned* hz = &hist[0][0];
        for (int i = tid; i < NWAVE * 256; i += NT) hz[i] = 0;
        for (int i = tid; i < 256; i += NT) fhist[i] = 0;
        if (tid == 0) { sh_cnt = 0; sh_flag = 0; sh_kept = 0; }
    }
    __syncthreads();

    // ---- Phase 1: scores (registers) + per-wave coarse histogram ----
    // All 12 float4 loads issued before any compute (one HBM latency).
    unsigned sbv[BPT];
    {
        const float4* conf4 = reinterpret_cast<const float4*>(conf);
        const float4* iou4  = reinterpret_cast<const float4*>(iou);
        float4 cf[8], io[4];
        #pragma unroll
        for (int m = 0; m < 2; ++m)
            #pragma unroll
            for (int q = 0; q < 4; ++q)
                cf[m * 4 + q] = conf4[(m * NT + tid) * 4 + q];
        #pragma unroll
        for (int m = 0; m < 2; ++m)
            #pragma unroll
            for (int r = 0; r < 2; ++r)
                io[m * 2 + r] = iou4[(m * NT + tid) * 2 + r];

        #pragma unroll
        for (int m = 0; m < 2; ++m) {
            float sc[8], uu[8];
            #pragma unroll
            for (int q = 0; q < 4; ++q) {
                sc[2 * q]     = cf[m * 4 + q].y;
                sc[2 * q + 1] = cf[m * 4 + q].w;
            }
            #pragma unroll
            for (int r = 0; r < 2; ++r) {
                uu[4 * r + 0] = io[m * 2 + r].x; uu[4 * r + 1] = io[m * 2 + r].y;
                uu[4 * r + 2] = io[m * 2 + r].z; uu[4 * r + 3] = io[m * 2 + r].w;
            }
            #pragma unroll
            for (int q = 0; q < 8; ++q) {
                float u = fminf(fmaxf(uu[q], 0.0f), 1.0f);
                float s = sqrtf(sc[q] * u);
                unsigned sb = __float_as_uint(s);   // s >= 0 -> monotonic bits
                sbv[m * 8 + q] = sb;
                atomicAdd(&hist[tid >> 6][sb >> 24], 1u);
            }
        }
    }
    __syncthreads();

    // ---- Phase 2a: coarse threshold (wave-parallel suffix scan) ----
    if (tid < 64) {
        const int lane = tid;
        unsigned c0 = 0, c1 = 0, c2 = 0, c3 = 0;
        #pragma unroll
        for (int w = 0; w < NWAVE; ++w) {
            c0 += hist[w][4 * lane + 0];
            c1 += hist[w][4 * lane + 1];
            c2 += hist[w][4 * lane + 2];
            c3 += hist[w][4 * lane + 3];
        }
        int bs; unsigned ab;
        find_thresh(c0, c1, c2, c3, 0u, lane, bs, ab);
        if (lane == 0) { sh_B = bs; sh_above = ab; }
    }
    __syncthreads();
    const int B = sh_B;
    const unsigned above = sh_above;

    // ---- Phase 2b: fine histogram (register scan) ----
    #pragma unroll
    for (int k = 0; k < BPT; ++k) {
        unsigned sb = sbv[k];
        if ((int)(sb >> 24) == B) atomicAdd(&fhist[(sb >> 16) & 255u], 1u);
    }
    __syncthreads();

    if (tid < 64) {
        const int lane = tid;
        int fs; unsigned ab2;
        find_thresh(fhist[4 * lane + 0], fhist[4 * lane + 1],
                    fhist[4 * lane + 2], fhist[4 * lane + 3], above, lane, fs, ab2);
        if (lane == 0) sh_T = ((unsigned)B << 24) | ((unsigned)fs << 16);
    }
    __syncthreads();
    const unsigned T = sh_T;

    // ---- Phase 3: compact candidates (register scan; compiler wave-aggregates atomics) ----
    #pragma unroll
    for (int m = 0; m < 2; ++m) {
        #pragma unroll
        for (int q = 0; q < 8; ++q) {
            unsigned sb = sbv[m * 8 + q];
            if (sb >= T) {
                unsigned pos = atomicAdd(&sh_cnt, 1u);
                if (pos < CAND_MAX)
                    cand[pos] = ((unsigned long long)(~sb) << 32)
                              | (unsigned)((m * NT + tid) * BPT / 2 + q);
            }
        }
    }
    __syncthreads();
    const int C = (int)sh_cnt;

    if (C <= CAND_MAX) {
        // ---- Phase 4: exact rank sort into keys[0..C) (keys unique) ----
        for (int i = tid; i < C; i += NT) {
            unsigned long long k = cand[i];
            int r = 0;
            int j = 0;
            for (; j + 4 <= C; j += 4) {
                r += (cand[j]     < k) ? 1 : 0;
                r += (cand[j + 1] < k) ? 1 : 0;
                r += (cand[j + 2] < k) ? 1 : 0;
                r += (cand[j + 3] < k) ? 1 : 0;
            }
            for (; j < C; ++j) r += (cand[j] < k) ? 1 : 0;
            keys[r] = k;
        }
        __syncthreads();

        // ---- Phase 5: block-parallel batch-mask greedy NMS ----
        for (int p = 0; p < C; p += 64) {
            // A: wave 0 decodes batch + tests vs previously-kept boxes
            if (tid < 64) {
                const int lane = tid;
                int pos = p + lane;
                bool valid = pos < C;
                int cidx = valid ? (int)(keys[pos] & 0xFFFFFFFFull) : 0;
                float x1, y1, x2, y2, area;
                decode_box(cidx, loc, priors, x1, y1, x2, y2, area);
                boxb4[lane] = make_float4(x1, y1, x2, y2);
                boxa[lane] = area;
                int kept = sh_kept;
                bool supP = !valid;
                for (int j = 0; j < kept; ++j) {
                    float4 kb = keptb4[j]; float ka = kepta[j];
                    float iw = fmaxf(fminf(x2, kb.z) - fmaxf(x1, kb.x), 0.f);
                    float ih = fmaxf(fminf(y2, kb.w) - fmaxf(y1, kb.y), 0.f);
                    float inter = iw * ih;
                    supP = supP || (inter > IOU_THR * (area + ka - inter));
                }
                unsigned long long sp = __ballot(supP);
                if (lane == 0) sh_supprev = sp;
            }
            __syncthreads();

            // B: all 512 threads build the 64x64 IoU bit-matrix (8 pairs each)
            {
                int r  = tid >> 3;
                int cb = tid & 7;
                float4 rb = boxb4[r]; float ra = boxa[r];
                unsigned byte = 0;
                #pragma unroll
                for (int k = 0; k < 8; ++k) {
                    int c = cb * 8 + k;
                    float4 cx = boxb4[c]; float ca = boxa[c];
                    float iw = fmaxf(fminf(rb.z, cx.z) - fmaxf(rb.x, cx.x), 0.f);
                    float ih = fmaxf(fminf(rb.w, cx.w) - fmaxf(rb.y, cx.y), 0.f);
                    float inter = iw * ih;
                    byte |= (unsigned)((inter > IOU_THR * (ra + ca - inter)) ? 1u : 0u) << k;
                }
                ((unsigned char*)maskbuf)[tid] = (unsigned char)byte;
            }
            __syncthreads();

            // C: wave 0 runs the exact greedy recurrence via shfl broadcast
            if (tid < 64) {
                const int lane = tid;
                unsigned long long mymask = maskbuf[lane];
                unsigned long long sup_prev = sh_supprev;
                unsigned long long keepcur = 0ull;
                for (int i2 = 0; i2 < 64; ++i2) {
                    unsigned long long mi = __shfl(mymask, i2);
                    unsigned long long lower = (i2 == 0) ? 0ull : (~0ull >> (64 - i2));
                    if (!((sup_prev >> i2) & 1ull) && !(mi & keepcur & lower))
                        keepcur |= (1ull << i2);
                }
                int kept = sh_kept;
                unsigned long long lowm = (lane == 0) ? 0ull : (~0ull >> (64 - lane));
                int rank = kept + __popcll(keepcur & lowm);
                if (((keepcur >> lane) & 1ull) && rank < TOP_K) {
                    keep_sh[rank] = (int)(keys[p + lane] & 0xFFFFFFFFull);
                    keptb4[rank] = boxb4[lane];
                    kepta[rank] = boxa[lane];
                }
                if (lane == 0) sh_kept = kept + __popcll(keepcur);
            }
            __syncthreads();
            if (sh_kept >= TOP_K) break;
        }
        if (tid == 0) sh_flag = (sh_kept >= TOP_K) ? 0 : 1;
    } else {
        if (tid == 0) sh_flag = 1;
    }
    __syncthreads();

    // ---- Fallback: exact full path ----
    if (sh_flag) {
        #pragma unroll
        for (int m = 0; m < 2; ++m) {
            #pragma unroll
            for (int q = 0; q < 8; ++q) {
                int i = (m * NT + tid) * 8 + q;
                keys[i] = ((unsigned long long)(~sbv[m * 8 + q]) << 32) | (unsigned)i;
            }
        }
        __syncthreads();
        bitonic_sort(keys, NBOX, tid);
        if (tid < 64) greedy_nms_serial(keys, NBOX, tid, loc, priors, keep_sh);
        __syncthreads();
    }

    // ---- Phase 6: gather + decode output rows ----
    if (tid < TOP_K) {
        int i = keep_sh[tid];
        float4 pr = *reinterpret_cast<const float4*>(priors + 4 * i);
        float cx = pr.x + loc[i * 14 + 0] * VAR0 * pr.z;
        float cy = pr.y + loc[i * 14 + 1] * VAR0 * pr.w;
        float hw = pr.z * expf(loc[i * 14 + 2] * VAR0) * 0.5f;
        float hh = pr.w * expf(loc[i * 14 + 3] * VAR1) * 0.5f;
        float* o = out + tid * 15;
        o[0] = cx - hw;
        o[1] = cy - hh;
        o[2] = cx + hw;
        o[3] = cy + hh;
        #pragma unroll
        for (int q = 0; q < 5; ++q) {
            o[4 + 2 * q] = pr.x + loc[i * 14 + 4 + 2 * q] * VAR0 * pr.z;
            o[5 + 2 * q] = pr.y + loc[i * 14 + 5 + 2 * q] * VAR0 * pr.w;
        }
        float cc = conf[i * 2 + 1];
        float u  = fminf(fmaxf(iou[i], 0.0f), 1.0f);
        o[14] = sqrtf(cc * u);
    }
}

extern "C" void kernel_launch(void* const* d_in, const int* in_sizes, int n_in,
                              void* d_out, int out_size, void* d_ws, size_t ws_size,
                              hipStream_t stream) {
    const float* loc    = (const float*)d_in[0];
    const float* conf   = (const float*)d_in[1];
    const float* iou    = (const float*)d_in[2];
    const float* priors = (const float*)d_in[3];
    float* out = (float*)d_out;

    yunet_fused_kernel<<<1, NT, 0, stream>>>(loc, conf, iou, priors, out);
}

// Round 5
// 23.181 us; speedup vs baseline: 4.8361x; 1.0039x over previous
//
#include <hip/hip_runtime.h>

#define NBOX 8192
#define TOP_K 50
#define IOU_THR 0.3f
#define VAR0 0.1f
#define VAR1 0.2f
#define NT 512
#define NWAVE (NT / 64)
#define MSEL 128
#define PRE_MAX 256     // candidate capacity (C in [128,~140] expected)
#define BPT 16          // boxes per thread

__device__ __forceinline__ void decode_box(int cidx, const float* __restrict__ loc,
                                           const float* __restrict__ priors,
                                           float& x1, float& y1, float& x2, float& y2,
                                           float& area)
{
    float4 pr = *reinterpret_cast<const float4*>(priors + 4 * cidx);
    float l0 = loc[cidx * 14 + 0];
    float l1 = loc[cidx * 14 + 1];
    float l2 = loc[cidx * 14 + 2];
    float l3 = loc[cidx * 14 + 3];
    float cx = pr.x + l0 * VAR0 * pr.z;
    float cy = pr.y + l1 * VAR0 * pr.w;
    float hw = pr.z * expf(l2 * VAR0) * 0.5f;
    float hh = pr.w * expf(l3 * VAR1) * 0.5f;
    x1 = cx - hw; y1 = cy - hh; x2 = cx + hw; y2 = cy + hh;
    area = (x2 - x1) * (y2 - y1);
}

// Per-wave: bins[4*lane .. 4*lane+3] (c0..c3), higher bin = higher score.
// Finds largest bin B with suffix count >= MSEL.
__device__ __forceinline__ void find_thresh(unsigned c0, unsigned c1, unsigned c2, unsigned c3,
                                            unsigned base_above, int lane,
                                            int& bin_sel, unsigned& above_sel)
{
    unsigned cnt = c0 + c1 + c2 + c3;
    unsigned S = cnt;                       // suffix sum over lanes >= lane
    #pragma unroll
    for (int d = 1; d < 64; d <<= 1) {
        unsigned t = __shfl_down(S, d);
        if (lane + d < 64) S += t;
    }
    unsigned long long bal = __ballot(base_above + S >= MSEL);
    int lstar = 63 - __clzll(bal);
    int src = (lstar < 63) ? (lstar + 1) : lstar;
    unsigned Snext = __shfl(S, src);
    unsigned above = base_above + ((lstar < 63) ? Snext : 0u);
    unsigned bl[4] = {c0, c1, c2, c3};
    int bsel = -1; unsigned abv = above; unsigned acc = above;
    #pragma unroll
    for (int k = 3; k >= 0; --k) {
        if (bsel < 0) {
            if (acc + bl[k] >= MSEL) { bsel = k; abv = acc; }
            else acc += bl[k];
        }
    }
    bin_sel  = 4 * lstar + __shfl(bsel, lstar);
    above_sel = __shfl(abv, lstar);
}

// ---- fallback machinery (exact; never taken on this data) ----
__device__ void bitonic_sort(unsigned long long* a, int S, int tid)
{
    for (int k = 2; k <= S; k <<= 1) {
        for (int j = k >> 1; j > 0; j >>= 1) {
            __syncthreads();
            for (int i = tid; i < S; i += NT) {
                int l = i ^ j;
                if (l > i) {
                    unsigned long long A = a[i];
                    unsigned long long B = a[l];
                    bool asc = ((i & k) == 0);
                    if ((A > B) == asc) { a[i] = B; a[l] = A; }
                }
            }
        }
    }
    __syncthreads();
}

__device__ int greedy_nms_serial(const unsigned long long* __restrict__ arr, int n, int lane,
                                 const float* __restrict__ loc, const float* __restrict__ priors,
                                 int* keep_out)
{
    float kx1 = 0.f, ky1 = 0.f, kx2 = 0.f, ky2 = 0.f, karea = 0.f;
    int my_keep = 0, idx0 = 0, kept = 0;
    bool done = false;
    for (int p = 0; p < n && !done; p += 64) {
        int cidx = 0;
        float x1 = 0.f, y1 = 0.f, x2 = 0.f, y2 = 0.f, area = 0.f;
        int pos = p + lane;
        if (pos < n) {
            cidx = (int)(arr[pos] & 0xFFFFFFFFull);
            decode_box(cidx, loc, priors, x1, y1, x2, y2, area);
        }
        int nb = (n - p) < 64 ? (n - p) : 64;
        for (int c = 0; c < nb; ++c) {
            float bx1 = __shfl(x1, c);
            float by1 = __shfl(y1, c);
            float bx2 = __shfl(x2, c);
            float by2 = __shfl(y2, c);
            float barea = __shfl(area, c);
            int   bidx  = __shfl(cidx, c);
            float iw = fmaxf(fminf(kx2, bx2) - fmaxf(kx1, bx1), 0.0f);
            float ih = fmaxf(fminf(ky2, by2) - fmaxf(ky1, by1), 0.0f);
            float inter = iw * ih;
            float v = inter / (karea + barea - inter);
            bool sup = (lane < kept) && (v > IOU_THR);
            if (__ballot(sup) == 0ull) {
                if (kept == 0) idx0 = bidx;
                if (lane == kept) {
                    kx1 = bx1; ky1 = by1; kx2 = bx2; ky2 = by2; karea = barea;
                    my_keep = bidx;
                }
                ++kept;
                if (kept == TOP_K) { done = true; break; }
            }
        }
    }
    if (lane < TOP_K) keep_out[lane] = (lane < kept) ? my_keep : idx0;
    return kept;
}

__global__ __launch_bounds__(NT) void yunet_fused_kernel(
    const float* __restrict__ loc,    // [NBOX][14]
    const float* __restrict__ conf,   // [NBOX][2]
    const float* __restrict__ iou,    // [NBOX][1]
    const float* __restrict__ priors, // [NBOX][4]
    float* __restrict__ out)          // [TOP_K][15]
{
    __shared__ unsigned long long keys[NBOX];     // fallback space; main path: sorted cands
    __shared__ unsigned long long cand[PRE_MAX];
    __shared__ unsigned hist[NWAVE][256] __attribute__((aligned(16)));
    __shared__ unsigned long long maskbuf[64];
    __shared__ unsigned long long sh_supprev;
    __shared__ float4 boxs4[PRE_MAX];             // decoded boxes, sorted order
    __shared__ float  boxsa[PRE_MAX];
    __shared__ float4 keptb4[TOP_K];
    __shared__ float  kepta[TOP_K];
    __shared__ int keep_sh[TOP_K];
    __shared__ unsigned sh_cnt;
    __shared__ int sh_flag, sh_kept;

    const int tid = threadIdx.x;
    const int lane = tid & 63;

    // ---- Phase 1a: issue all global loads first (latency hides under zeroing) ----
    const float4* conf4 = reinterpret_cast<const float4*>(conf);
    const float4* iou4  = reinterpret_cast<const float4*>(iou);
    float4 cf[8], io[4];
    #pragma unroll
    for (int m = 0; m < 2; ++m)
        #pragma unroll
        for (int q = 0; q < 4; ++q)
            cf[m * 4 + q] = conf4[(m * NT + tid) * 4 + q];
    #pragma unroll
    for (int m = 0; m < 2; ++m)
        #pragma unroll
        for (int r = 0; r < 2; ++r)
            io[m * 2 + r] = iou4[(m * NT + tid) * 2 + r];

    // ---- Phase 0: zero histograms/control ----
    {
        unsigned* hz = &hist[0][0];
        for (int i = tid; i < NWAVE * 256; i += NT) hz[i] = 0;
        if (tid == 0) { sh_cnt = 0; sh_flag = 0; sh_kept = 0; }
    }
    __syncthreads();

    // ---- Phase 1b: scores (registers) + per-wave LINEAR-bin histogram ----
    // bin = (int)(s*256): spreads counts (~<=11/bin) -> low atomic contention,
    // and one coarse pass bounds C to [MSEL, MSEL+binwidth].
    unsigned sbv[BPT];
    #pragma unroll
    for (int m = 0; m < 2; ++m) {
        float sc[8], uu[8];
        #pragma unroll
        for (int q = 0; q < 4; ++q) {
            sc[2 * q]     = cf[m * 4 + q].y;
            sc[2 * q + 1] = cf[m * 4 + q].w;
        }
        #pragma unroll
        for (int r = 0; r < 2; ++r) {
            uu[4 * r + 0] = io[m * 2 + r].x; uu[4 * r + 1] = io[m * 2 + r].y;
            uu[4 * r + 2] = io[m * 2 + r].z; uu[4 * r + 3] = io[m * 2 + r].w;
        }
        #pragma unroll
        for (int q = 0; q < 8; ++q) {
            float u = fminf(fmaxf(uu[q], 0.0f), 1.0f);
            float s = sqrtf(sc[q] * u);
            unsigned sb = __float_as_uint(s);   // s >= 0 -> monotonic bits
            sbv[m * 8 + q] = sb;
            int bin = (int)(s * 256.0f); bin = bin > 255 ? 255 : bin;
            atomicAdd(&hist[tid >> 6][bin], 1u);
        }
    }
    __syncthreads();

    // ---- Phase 2: threshold bin B (wave-redundant: every wave computes it) ----
    int B;
    {
        unsigned c0 = 0, c1 = 0, c2 = 0, c3 = 0;
        #pragma unroll
        for (int w = 0; w < NWAVE; ++w) {
            uint4 h = *(const uint4*)&hist[w][4 * lane];
            c0 += h.x; c1 += h.y; c2 += h.z; c3 += h.w;
        }
        unsigned ab;
        find_thresh(c0, c1, c2, c3, 0u, lane, B, ab);
    }

    // ---- Phase 3: compact candidates with bin >= B (register scan) ----
    #pragma unroll
    for (int m = 0; m < 2; ++m) {
        #pragma unroll
        for (int q = 0; q < 8; ++q) {
            unsigned sb = sbv[m * 8 + q];
            float s = __uint_as_float(sb);
            int bin = (int)(s * 256.0f); bin = bin > 255 ? 255 : bin;
            if (bin >= B) {
                unsigned pos = atomicAdd(&sh_cnt, 1u);
                if (pos < PRE_MAX)
                    cand[pos] = ((unsigned long long)(~sb) << 32)
                              | (unsigned)((m * NT + tid) * 8 + q);
            }
        }
    }
    __syncthreads();
    const int C = (int)sh_cnt;

    if (C <= PRE_MAX) {
        // ---- Phase 4: rank sort (exact; keys unique) + parallel box decode ----
        if (tid < C) {
            unsigned long long k = cand[tid];
            int r = 0, j = 0;
            for (; j + 4 <= C; j += 4) {
                r += (cand[j]     < k) ? 1 : 0;
                r += (cand[j + 1] < k) ? 1 : 0;
                r += (cand[j + 2] < k) ? 1 : 0;
                r += (cand[j + 3] < k) ? 1 : 0;
            }
            for (; j < C; ++j) r += (cand[j] < k) ? 1 : 0;
            keys[r] = k;
            int cidx = (int)(k & 0xFFFFFFFFull);
            float x1, y1, x2, y2, area;
            decode_box(cidx, loc, priors, x1, y1, x2, y2, area);
            boxs4[r] = make_float4(x1, y1, x2, y2);
            boxsa[r] = area;
        }
        __syncthreads();

        // ---- Phase 5: batch-mask greedy NMS (boxes from LDS, no global gathers) ----
        for (int p = 0; p < C; p += 64) {
            // A: wave 0 tests batch vs previously-kept boxes
            if (tid < 64) {
                int pos = p + lane;
                bool valid = pos < C;
                int rp = valid ? pos : 0;
                float4 b = boxs4[rp]; float a = boxsa[rp];
                int kept = sh_kept;
                bool supP = !valid;
                for (int j = 0; j < kept; ++j) {
                    float4 kb = keptb4[j]; float ka = kepta[j];
                    float iw = fmaxf(fminf(b.z, kb.z) - fmaxf(b.x, kb.x), 0.f);
                    float ih = fmaxf(fminf(b.w, kb.w) - fmaxf(b.y, kb.y), 0.f);
                    float inter = iw * ih;
                    supP = supP || (inter > IOU_THR * (a + ka - inter));
                }
                unsigned long long sp = __ballot(supP);
                if (lane == 0) sh_supprev = sp;
            }
            __syncthreads();

            // B: all 512 threads build the 64x64 IoU bit-matrix (8 pairs each)
            {
                int r  = tid >> 3;
                int cb = tid & 7;
                int rp = (p + r < C) ? p + r : 0;
                float4 rb = boxs4[rp]; float ra = boxsa[rp];
                unsigned byte = 0;
                #pragma unroll
                for (int k = 0; k < 8; ++k) {
                    int c = cb * 8 + k;
                    int cp = (p + c < C) ? p + c : 0;
                    float4 cx = boxs4[cp]; float ca = boxsa[cp];
                    float iw = fmaxf(fminf(rb.z, cx.z) - fmaxf(rb.x, cx.x), 0.f);
                    float ih = fmaxf(fminf(rb.w, cx.w) - fmaxf(rb.y, cx.y), 0.f);
                    float inter = iw * ih;
                    byte |= (unsigned)((inter > IOU_THR * (ra + ca - inter)) ? 1u : 0u) << k;
                }
                ((unsigned char*)maskbuf)[tid] = (unsigned char)byte;
            }
            __syncthreads();

            // C: wave 0 exact greedy recurrence via shfl broadcast
            if (tid < 64) {
                unsigned long long mymask = maskbuf[lane];
                unsigned long long sup_prev = sh_supprev;
                unsigned long long keepcur = 0ull;
                const int kept0 = sh_kept;
                int kept = kept0;
                for (int i2 = 0; i2 < 64 && kept < TOP_K; ++i2) {
                    unsigned long long mi = __shfl(mymask, i2);
                    unsigned long long lower = (1ull << i2) - 1ull;
                    if (!((sup_prev >> i2) & 1ull) && !(mi & keepcur & lower)) {
                        keepcur |= 1ull << i2;
                        ++kept;
                    }
                }
                unsigned long long lowm = (1ull << lane) - 1ull;
                int rank = kept0 + __popcll(keepcur & lowm);
                if (((keepcur >> lane) & 1ull) && rank < TOP_K) {
                    int pos = p + lane;
                    keep_sh[rank] = (int)(keys[pos] & 0xFFFFFFFFull);
                    keptb4[rank] = boxs4[pos];
                    kepta[rank] = boxsa[pos];
                }
                if (lane == 0) sh_kept = kept;
            }
            __syncthreads();
            if (sh_kept >= TOP_K) break;
        }
        if (tid == 0) sh_flag = (sh_kept >= TOP_K) ? 0 : 1;
    } else {
        if (tid == 0) sh_flag = 1;
    }
    __syncthreads();

    // ---- Fallback: exact full path ----
    if (sh_flag) {
        #pragma unroll
        for (int m = 0; m < 2; ++m) {
            #pragma unroll
            for (int q = 0; q < 8; ++q) {
                int i = (m * NT + tid) * 8 + q;
                keys[i] = ((unsigned long long)(~sbv[m * 8 + q]) << 32) | (unsigned)i;
            }
        }
        __syncthreads();
        bitonic_sort(keys, NBOX, tid);
        if (tid < 64) greedy_nms_serial(keys, NBOX, tid, loc, priors, keep_sh);
        if (tid == 0) sh_kept = TOP_K;   // serial path fills all TOP_K slots
        __syncthreads();
    }

    // ---- Phase 6: gather + decode output rows ----
    if (tid < TOP_K) {
        int src = (tid < sh_kept) ? tid : 0;   // fill = first kept index
        int i = keep_sh[src];
        float4 pr = *reinterpret_cast<const float4*>(priors + 4 * i);
        float cx = pr.x + loc[i * 14 + 0] * VAR0 * pr.z;
        float cy = pr.y + loc[i * 14 + 1] * VAR0 * pr.w;
        float hw = pr.z * expf(loc[i * 14 + 2] * VAR0) * 0.5f;
        float hh = pr.w * expf(loc[i * 14 + 3] * VAR1) * 0.5f;
        float* o = out + tid * 15;
        o[0] = cx - hw;
        o[1] = cy - hh;
        o[2] = cx + hw;
        o[3] = cy + hh;
        #pragma unroll
        for (int q = 0; q < 5; ++q) {
            o[4 + 2 * q] = pr.x + loc[i * 14 + 4 + 2 * q] * VAR0 * pr.z;
            o[5 + 2 * q] = pr.y + loc[i * 14 + 5 + 2 * q] * VAR0 * pr.w;
        }
        float cc = conf[i * 2 + 1];
        float u  = fminf(fmaxf(iou[i], 0.0f), 1.0f);
        o[14] = sqrtf(cc * u);
    }
}

extern "C" void kernel_launch(void* const* d_in, const int* in_sizes, int n_in,
                              void* d_out, int out_size, void* d_ws, size_t ws_size,
                              hipStream_t stream) {
    const float* loc    = (const float*)d_in[0];
    const float* conf   = (const float*)d_in[1];
    const float* iou    = (const float*)d_in[2];
    const float* priors = (const float*)d_in[3];
    float* out = (float*)d_out;

    yunet_fused_kernel<<<1, NT, 0, stream>>>(loc, conf, iou, priors, out);
}